// Round 2
// baseline (937.871 us; speedup 1.0000x reference)
//
#include <hip/hip_runtime.h>

typedef unsigned short u16;
typedef __bf16 bf16x8 __attribute__((ext_vector_type(8)));
typedef float f32x4 __attribute__((ext_vector_type(4)));
typedef u16 u16x8 __attribute__((ext_vector_type(8)));

// ---------- helpers ----------
__device__ __forceinline__ u16 f2bf(float f) {
  unsigned u = __builtin_bit_cast(unsigned, f);
  return (u16)((u + 0x7fffu + ((u >> 16) & 1u)) >> 16);
}

__device__ __forceinline__ void async_load16(const void* g, void* l) {
  __builtin_amdgcn_global_load_lds((const __attribute__((address_space(1))) void*)g,
                                   (__attribute__((address_space(3))) void*)l,
                                   16, 0, 0);
}

// ---------- pad + cast x: (1024,784) f32 -> (1024,800) bf16 ----------
__global__ void pad_x_k(const float* __restrict__ x, u16* __restrict__ xbf) {
  int idx = blockIdx.x * 256 + threadIdx.x;          // 1024*800
  int m = idx / 800, k = idx - m * 800;
  float v = (k < 784) ? x[m * 784 + k] : 0.f;
  xbf[idx] = f2bf(v);
}

// ---------- fused sample + transpose (no LDS) ----------
// wt[s][n][k] = f2bf( we[s][k][n]*exp(0.5*wv[k][n]) + wm[k][n] ), k in [0,Kp) zero-padded.
// Lane owns row n; reads coalesced 4B/lane along n; writes 16B/lane along k.
// Block mapping (SC>=8): b = g | (inner<<3), g = XCD lane = s%8, spg = SC/8 samples/block.
// k-chunk = 64 k (8 octets); wm/exp(0.5*wv) held in regs across the s sub-loop.
__global__ __launch_bounds__(256) void sample_wt_k(
    const float* __restrict__ we,   // chunk base: (SC,K,N)
    const float* __restrict__ wm,   // (K,N)
    const float* __restrict__ wv,   // (K,N)
    u16* __restrict__ wt,           // (SC,N,Kp)
    int K, int N, int Kp, int SC) {
  int b = blockIdx.x;
  int g, inner, spg;
  if (SC >= 8) { g = b & 7; inner = b >> 3; spg = SC >> 3; }
  else         { g = b & (SC - 1); inner = b / SC; spg = 1; }
  const int NB4 = N >> 8;                 // 256 n per block
  const int n4 = inner & (NB4 - 1);
  const int kc = inner / NB4;             // 64-k chunk index
  const int t = threadIdx.x;
  const int n = (n4 << 8) + t;            // 256 consecutive n per block

#pragma unroll 2
  for (int ko = 0; ko < 8; ++ko) {
    const int kbase = (kc << 6) + (ko << 3);
    if (kbase >= Kp) break;
    float wmr[8], sc[8];
#pragma unroll
    for (int j = 0; j < 8; ++j) {
      int k = kbase + j;
      bool ok = (k < K);
      size_t idx = (size_t)k * N + n;
      wmr[j] = ok ? wm[idx] : 0.f;
      sc[j]  = ok ? __expf(0.5f * wv[idx]) : 0.f;
    }
    for (int si = 0; si < spg; ++si) {
      const int s = g + (si << 3);
      const float* we_s = we + (size_t)s * K * N;
      u16x8 pk;
#pragma unroll
      for (int j = 0; j < 8; ++j) {
        int k = kbase + j;
        float v = (k < K) ? fmaf(sc[j], we_s[(size_t)k * N + n], wmr[j]) : 0.f;
        pk[j] = f2bf(v);
      }
      *(u16x8*)(wt + ((size_t)s * N + n) * Kp + kbase) = pk;
    }
  }
}

// ---------- sample last-layer W -> Wlt[s][16][1024] bf16 (n>=10 zero) ----------
__global__ void sample_wl_k(const float* __restrict__ wel,  // chunk base (SC,1024,10)
                            const float* __restrict__ wlm,  // (1024,10)
                            const float* __restrict__ wlv,  // (1024,10)
                            u16* __restrict__ wlt) {        // (SC,16,1024)
  int idx = blockIdx.x * 256 + threadIdx.x;   // SC*16*1024
  int k = idx & 1023;
  int n = (idx >> 10) & 15;
  int s = idx >> 14;
  float v = 0.f;
  if (n < 10) {
    size_t i2 = ((size_t)s * 1024 + k) * 10 + n;
    size_t iw = (size_t)k * 10 + n;
    v = fmaf(__expf(0.5f * wlv[iw]), wel[i2], wlm[iw]);
  }
  wlt[idx] = f2bf(v);
}

// ---------- batched GEMM: C[s] = relu(A[s] @ Bt[s]^T + bias[s]) ----------
// 1D grid, XCD swizzle: sample s -> XCD s%8 so one sample's 64 tiles share one L2.
__global__ __launch_bounds__(256) void gemm_bt_relu(
    const u16* __restrict__ A, size_t strideAs, int ldA,
    const u16* __restrict__ Bt,
    u16* __restrict__ C,
    int K,
    const float* __restrict__ bm, const float* __restrict__ bv,
    const float* __restrict__ be, int s_off, int SC) {
  __shared__ __align__(16) u16 As[128 * 32];
  __shared__ __align__(16) u16 Bs[128 * 32];

  const int b = blockIdx.x;
  int sc, tile;
  if (SC >= 8) { sc = (b & 7) + ((b >> 9) << 3); tile = (b >> 3) & 63; }
  else         { sc = b >> 6; tile = b & 63; }
  const int sg = sc + s_off;
  const u16* A_s = A + (size_t)sc * strideAs;
  const u16* B_s = Bt + (size_t)sc * (size_t)1024 * K;
  u16* C_s = C + (size_t)sc * (size_t)1024 * 1024;

  const int m0 = (tile >> 3) * 128;
  const int n0 = (tile & 7) * 128;
  const int t = threadIdx.x;
  const int w = t >> 6, l = t & 63;
  const int quad = l >> 4, lane16 = l & 15;
  const int wm_ = (w >> 1) * 64, wn_ = (w & 1) * 64;

  f32x4 acc[4][4];
#pragma unroll
  for (int i = 0; i < 4; ++i)
#pragma unroll
    for (int j = 0; j < 4; ++j) acc[i][j] = (f32x4){0.f, 0.f, 0.f, 0.f};

  for (int k0 = 0; k0 < K; k0 += 32) {
    __syncthreads();  // previous tile's readers done
#pragma unroll
    for (int i = 0; i < 2; ++i) {
      int p = w * 128 + i * 64 + l;                 // 16B chunk id
      const u16* srcA = A_s + (size_t)(m0 + (p >> 2)) * ldA + k0 + (p & 3) * 8;
      async_load16(srcA, &As[(size_t)(w * 128 + i * 64) * 8]);
      const u16* srcB = B_s + (size_t)(n0 + (p >> 2)) * K + k0 + (p & 3) * 8;
      async_load16(srcB, &Bs[(size_t)(w * 128 + i * 64) * 8]);
    }
    __syncthreads();  // staging complete

    bf16x8 af[4], bfr[4];
#pragma unroll
    for (int mi = 0; mi < 4; ++mi)
      af[mi] = *(const bf16x8*)&As[(wm_ + mi * 16 + lane16) * 32 + quad * 8];
#pragma unroll
    for (int ni = 0; ni < 4; ++ni)
      bfr[ni] = *(const bf16x8*)&Bs[(wn_ + ni * 16 + lane16) * 32 + quad * 8];
#pragma unroll
    for (int mi = 0; mi < 4; ++mi)
#pragma unroll
      for (int ni = 0; ni < 4; ++ni)
        acc[mi][ni] =
            __builtin_amdgcn_mfma_f32_16x16x32_bf16(af[mi], bfr[ni], acc[mi][ni], 0, 0, 0);
  }

  // epilogue: bias (sampled on the fly) + relu + bf16 store
#pragma unroll
  for (int ni = 0; ni < 4; ++ni) {
    int n = n0 + wn_ + ni * 16 + lane16;
    float bias = fmaf(__expf(0.5f * bv[n]), be[(size_t)sg * 1024 + n], bm[n]);
#pragma unroll
    for (int mi = 0; mi < 4; ++mi) {
#pragma unroll
      for (int r = 0; r < 4; ++r) {
        int m = m0 + wm_ + mi * 16 + quad * 4 + r;
        float v = acc[mi][ni][r] + bias;
        v = fmaxf(v, 0.f);
        C_s[(size_t)m * 1024 + n] = f2bf(v);
      }
    }
  }
}

// ---------- final layer: logits[s] = act2[s] @ Wl[s] + bl[s], N=10 ----------
__global__ __launch_bounds__(256) void gemm_last_k(
    const u16* __restrict__ act2, const u16* __restrict__ Wlt,
    float* __restrict__ out,
    const float* __restrict__ blm, const float* __restrict__ blv,
    const float* __restrict__ bel, int s_off, int SC) {
  const int b = blockIdx.x;
  int sc, tile;
  if (SC >= 8) { int g = b & 7, r = b >> 3; tile = r & 15; sc = g + ((r >> 4) << 3); }
  else         { sc = b >> 4; tile = b & 15; }
  const int sg = sc + s_off;
  const int t = threadIdx.x;
  const int w = t >> 6, l = t & 63;
  const int quad = l >> 4, lane16 = l & 15;
  const int m0 = (tile * 4 + w) * 16;  // 64 m-tiles per sample

  const u16* A_s = act2 + (size_t)sc * 1024 * 1024;
  const u16* B_s = Wlt + (size_t)sc * 16 * 1024;

  f32x4 acc = (f32x4){0.f, 0.f, 0.f, 0.f};
#pragma unroll 4
  for (int k0 = 0; k0 < 1024; k0 += 32) {
    bf16x8 a = *(const bf16x8*)&A_s[(size_t)(m0 + lane16) * 1024 + k0 + quad * 8];
    bf16x8 bb = *(const bf16x8*)&B_s[(size_t)lane16 * 1024 + k0 + quad * 8];
    acc = __builtin_amdgcn_mfma_f32_16x16x32_bf16(a, bb, acc, 0, 0, 0);
  }
  int n = lane16;
  if (n < 10) {
    float bias = fmaf(__expf(0.5f * blv[n]), bel[sg * 10 + n], blm[n]);
#pragma unroll
    for (int r = 0; r < 4; ++r) {
      int m = m0 + quad * 4 + r;
      out[((size_t)sg * 1024 + m) * 10 + n] = acc[r] + bias;
    }
  }
}

// ---------- launch ----------
extern "C" void kernel_launch(void* const* d_in, const int* in_sizes, int n_in,
                              void* d_out, int out_size, void* d_ws, size_t ws_size,
                              hipStream_t stream) {
  const float* x   = (const float*)d_in[0];
  const float* wm0 = (const float*)d_in[1];
  const float* wv0 = (const float*)d_in[2];
  const float* bm0 = (const float*)d_in[3];
  const float* bv0 = (const float*)d_in[4];
  const float* wm1 = (const float*)d_in[5];
  const float* wv1 = (const float*)d_in[6];
  const float* bm1 = (const float*)d_in[7];
  const float* bv1 = (const float*)d_in[8];
  const float* wlm = (const float*)d_in[9];
  const float* wlv = (const float*)d_in[10];
  const float* blm = (const float*)d_in[11];
  const float* blv = (const float*)d_in[12];
  const float* we0 = (const float*)d_in[13];
  const float* be0 = (const float*)d_in[14];
  const float* we1 = (const float*)d_in[15];
  const float* be1 = (const float*)d_in[16];
  const float* wel = (const float*)d_in[17];
  const float* bel = (const float*)d_in[18];
  float* out = (float*)d_out;

  // workspace layout
  const size_t sz_x    = (size_t)1024 * 800 * 2;
  const size_t sz_W0t  = (size_t)1024 * 800 * 2;   // per s
  const size_t sz_act  = (size_t)1024 * 1024 * 2;  // per s
  const size_t sz_Wlt  = (size_t)16 * 1024 * 2;    // per s
  const size_t per_s = sz_W0t + 3 * sz_act + sz_Wlt;

  int SC = 32;
  while (SC > 1 && sz_x + (size_t)SC * per_s + 4096 > ws_size) SC >>= 1;

  char* ws = (char*)d_ws;
  size_t off = 0;
  auto take = [&](size_t bsz) {
    char* p = ws + off;
    off = (off + bsz + 255) & ~(size_t)255;
    return p;
  };
  u16* xbf  = (u16*)take(sz_x);
  u16* W0t  = (u16*)take((size_t)SC * sz_W0t);
  u16* act1 = (u16*)take((size_t)SC * sz_act);
  u16* W1t  = (u16*)take((size_t)SC * sz_act);
  u16* act2 = (u16*)take((size_t)SC * sz_act);
  u16* Wlt  = (u16*)take((size_t)SC * sz_Wlt);

  pad_x_k<<<3200, 256, 0, stream>>>(x, xbf);

  const int gdim_s = (SC >= 8) ? 8 : SC;            // XCD-lane dimension
  const int kc0 = (800 + 63) / 64;                  // 13 k-chunks (layer0, Kp=800)
  const int kc1 = 1024 / 64;                        // 16 k-chunks (layer1)

  for (int s0 = 0; s0 < 32; s0 += SC) {
    // layer 0: K=784 (pad 800), N=1024
    sample_wt_k<<<gdim_s * 4 * kc0, 256, 0, stream>>>(
        we0 + (size_t)s0 * 784 * 1024, wm0, wv0, W0t, 784, 1024, 800, SC);
    gemm_bt_relu<<<64 * SC, 256, 0, stream>>>(
        xbf, (size_t)0, 800, W0t, act1, 800, bm0, bv0, be0, s0, SC);
    // layer 1: K=1024, N=1024
    sample_wt_k<<<gdim_s * 4 * kc1, 256, 0, stream>>>(
        we1 + (size_t)s0 * 1024 * 1024, wm1, wv1, W1t, 1024, 1024, 1024, SC);
    gemm_bt_relu<<<64 * SC, 256, 0, stream>>>(
        act1, (size_t)1024 * 1024, 1024, W1t, act2, 1024, bm1, bv1, be1, s0, SC);
    // last layer
    sample_wl_k<<<SC * 64, 256, 0, stream>>>(
        wel + (size_t)s0 * 1024 * 10, wlm, wlv, Wlt);
    gemm_last_k<<<16 * SC, 256, 0, stream>>>(
        act2, Wlt, out, blm, blv, bel, s0, SC);
  }
}

// Round 3
// 644.552 us; speedup vs baseline: 1.4551x; 1.4551x over previous
//
#include <hip/hip_runtime.h>

typedef unsigned short u16;
typedef __bf16 bf16x8 __attribute__((ext_vector_type(8)));
typedef float f32x4 __attribute__((ext_vector_type(4)));
typedef u16 u16x8 __attribute__((ext_vector_type(8)));

// ---------- helpers ----------
__device__ __forceinline__ u16 f2bf(float f) {
  unsigned u = __builtin_bit_cast(unsigned, f);
  return (u16)((u + 0x7fffu + ((u >> 16) & 1u)) >> 16);
}

__device__ __forceinline__ void async_load16(const void* g, void* l) {
  __builtin_amdgcn_global_load_lds((const __attribute__((address_space(1))) void*)g,
                                   (__attribute__((address_space(3))) void*)l,
                                   16, 0, 0);
}

// ---------- pad + cast x: (1024,784) f32 -> (1024,800) bf16 ----------
__global__ void pad_x_k(const float* __restrict__ x, u16* __restrict__ xbf) {
  int idx = blockIdx.x * 256 + threadIdx.x;          // 1024*800
  int m = idx / 800, k = idx - m * 800;
  float v = (k < 784) ? x[m * 784 + k] : 0.f;
  xbf[idx] = f2bf(v);
}

// ---------- fused sample + transpose into GEMM-tiled layout ----------
// wt per sample: [KB][1024 n][32 k] bf16, wt[s][kb][n][j] = sample(W[kb*32+j][n]).
// Lane owns (n, kb): reads we coalesced (256B/instr along n), writes 64B/lane
// contiguous (full cache lines). wm/exp(0.5*wv) amortized over spg samples.
// Block->XCD: g = b % gs = s % 8 lane, matching the GEMM's reader XCD.
__global__ __launch_bounds__(256) void sample_wt_k(
    const float* __restrict__ we,   // chunk base: (SC,K,N)
    const float* __restrict__ wm,   // (K,N)
    const float* __restrict__ wv,   // (K,N)
    u16* __restrict__ wt,           // (SC,KB,1024,32)
    int K, int KB, int SC) {
  const int N = 1024;
  const int b = blockIdx.x;
  const int gs = (SC >= 8) ? 8 : SC;
  const int g = b % gs;
  const int rest = b / gs;
  const int kb = rest % KB;
  const int nb = rest / KB;
  const int spg = SC / gs;
  const int n = nb * 256 + threadIdx.x;
  const int kbase = kb * 32;

  float wmr[32], sc[32];
#pragma unroll
  for (int j = 0; j < 32; ++j) {
    int k = kbase + j;
    bool ok = (k < K);
    size_t idx = (size_t)k * N + n;
    wmr[j] = ok ? wm[idx] : 0.f;
    sc[j]  = ok ? __expf(0.5f * wv[idx]) : 0.f;
  }
  for (int si = 0; si < spg; ++si) {
    const int s = g + si * gs;
    const float* we_s = we + (size_t)s * K * N;
    u16 pk[32];
#pragma unroll
    for (int j = 0; j < 32; ++j) {
      int k = kbase + j;
      float v = (k < K) ? fmaf(sc[j], we_s[(size_t)k * N + n], wmr[j]) : 0.f;
      pk[j] = f2bf(v);
    }
    u16* dst = wt + ((size_t)s * KB + kb) * ((size_t)N * 32) + (size_t)n * 32;
#pragma unroll
    for (int q = 0; q < 4; ++q)
      *(u16x8*)(dst + q * 8) = *(const u16x8*)(pk + q * 8);
  }
}

// ---------- sample last-layer W -> Wlt[s][16][1024] bf16 (n>=10 zero) ----------
__global__ void sample_wl_k(const float* __restrict__ wel,  // chunk base (SC,1024,10)
                            const float* __restrict__ wlm,  // (1024,10)
                            const float* __restrict__ wlv,  // (1024,10)
                            u16* __restrict__ wlt) {        // (SC,16,1024)
  int idx = blockIdx.x * 256 + threadIdx.x;   // SC*16*1024
  int k = idx & 1023;
  int n = (idx >> 10) & 15;
  int s = idx >> 14;
  float v = 0.f;
  if (n < 10) {
    size_t i2 = ((size_t)s * 1024 + k) * 10 + n;
    size_t iw = (size_t)k * 10 + n;
    v = fmaf(__expf(0.5f * wlv[iw]), wel[i2], wlm[iw]);
  }
  wlt[idx] = f2bf(v);
}

// ---------- batched GEMM: C[s] = relu(A[s] @ W[s] + bias[s]) ----------
// A: (1024, Kp) bf16 row-major (strideAs==0 -> shared A).
// Bt: tiled (Kp/32, 1024, 32) bf16 per sample. C: (1024,1024) bf16.
// 1D grid, XCD swizzle: sample s -> XCD s%8 (one sample's 4MB WS in one L2).
__global__ __launch_bounds__(256) void gemm_bt_relu(
    const u16* __restrict__ A, size_t strideAs, int ldA,
    const u16* __restrict__ Bt,
    u16* __restrict__ C,
    int Kp,
    const float* __restrict__ bm, const float* __restrict__ bv,
    const float* __restrict__ be, int s_off, int SC) {
  __shared__ __align__(16) u16 As[128 * 32];
  __shared__ __align__(16) u16 Bs[128 * 32];

  const int b = blockIdx.x;
  int sc, tile;
  if (SC >= 8) { sc = (b & 7) + ((b >> 9) << 3); tile = (b >> 3) & 63; }
  else         { sc = b >> 6; tile = b & 63; }
  const int sg = sc + s_off;
  const u16* A_s = A + (size_t)sc * strideAs;
  const u16* B_s = Bt + (size_t)sc * (size_t)1024 * Kp;  // per-sample tiled block
  u16* C_s = C + (size_t)sc * (size_t)1024 * 1024;

  const int m0 = (tile >> 3) * 128;
  const int n0 = (tile & 7) * 128;
  const int t = threadIdx.x;
  const int w = t >> 6, l = t & 63;
  const int quad = l >> 4, lane16 = l & 15;
  const int wm_ = (w >> 1) * 64, wn_ = (w & 1) * 64;

  f32x4 acc[4][4];
#pragma unroll
  for (int i = 0; i < 4; ++i)
#pragma unroll
    for (int j = 0; j < 4; ++j) acc[i][j] = (f32x4){0.f, 0.f, 0.f, 0.f};

  for (int k0 = 0; k0 < Kp; k0 += 32) {
    const u16* Bk = B_s + (size_t)(k0 >> 5) * (1024 * 32);
    __syncthreads();  // previous tile's readers done
#pragma unroll
    for (int i = 0; i < 2; ++i) {
      int p = w * 128 + i * 64 + l;                 // 16B chunk id
      const u16* srcA = A_s + (size_t)(m0 + (p >> 2)) * ldA + k0 + (p & 3) * 8;
      async_load16(srcA, &As[(size_t)(w * 128 + i * 64) * 8]);
      const u16* srcB = Bk + (size_t)(n0 + (p >> 2)) * 32 + (p & 3) * 8;
      async_load16(srcB, &Bs[(size_t)(w * 128 + i * 64) * 8]);
    }
    __syncthreads();  // staging complete

    bf16x8 af[4], bfr[4];
#pragma unroll
    for (int mi = 0; mi < 4; ++mi)
      af[mi] = *(const bf16x8*)&As[(wm_ + mi * 16 + lane16) * 32 + quad * 8];
#pragma unroll
    for (int ni = 0; ni < 4; ++ni)
      bfr[ni] = *(const bf16x8*)&Bs[(wn_ + ni * 16 + lane16) * 32 + quad * 8];
#pragma unroll
    for (int mi = 0; mi < 4; ++mi)
#pragma unroll
      for (int ni = 0; ni < 4; ++ni)
        acc[mi][ni] =
            __builtin_amdgcn_mfma_f32_16x16x32_bf16(af[mi], bfr[ni], acc[mi][ni], 0, 0, 0);
  }

  // epilogue: bias (sampled on the fly) + relu + bf16 store
#pragma unroll
  for (int ni = 0; ni < 4; ++ni) {
    int n = n0 + wn_ + ni * 16 + lane16;
    float bias = fmaf(__expf(0.5f * bv[n]), be[(size_t)sg * 1024 + n], bm[n]);
#pragma unroll
    for (int mi = 0; mi < 4; ++mi) {
#pragma unroll
      for (int r = 0; r < 4; ++r) {
        int m = m0 + wm_ + mi * 16 + quad * 4 + r;
        float v = acc[mi][ni][r] + bias;
        v = fmaxf(v, 0.f);
        C_s[(size_t)m * 1024 + n] = f2bf(v);
      }
    }
  }
}

// ---------- final layer: logits[s] = act2[s] @ Wl[s] + bl[s], N=10 ----------
// One 16-row m-tile per block; 4 waves split K=1024; LDS reduce.
__global__ __launch_bounds__(256) void gemm_last_k(
    const u16* __restrict__ act2, const u16* __restrict__ Wlt,
    float* __restrict__ out,
    const float* __restrict__ blm, const float* __restrict__ blv,
    const float* __restrict__ bel, int s_off) {
  __shared__ f32x4 red[4][64];
  const int b = blockIdx.x;
  const int sc = b >> 6, tile = b & 63;
  const int t = threadIdx.x;
  const int w = t >> 6, l = t & 63;
  const int quad = l >> 4, lane16 = l & 15;
  const int m0 = tile * 16;

  const u16* A_s = act2 + (size_t)sc * 1024 * 1024;
  const u16* B_s = Wlt + (size_t)sc * 16 * 1024;

  f32x4 acc = (f32x4){0.f, 0.f, 0.f, 0.f};
  const int kbase = w * 256;
#pragma unroll
  for (int k0 = 0; k0 < 256; k0 += 32) {
    int k = kbase + k0;
    bf16x8 a = *(const bf16x8*)&A_s[(size_t)(m0 + lane16) * 1024 + k + quad * 8];
    bf16x8 bb = *(const bf16x8*)&B_s[(size_t)lane16 * 1024 + k + quad * 8];
    acc = __builtin_amdgcn_mfma_f32_16x16x32_bf16(a, bb, acc, 0, 0, 0);
  }
  red[w][l] = acc;
  __syncthreads();
  if (w == 0) {
    f32x4 r = red[0][l];
#pragma unroll
    for (int ww = 1; ww < 4; ++ww) {
      f32x4 o = red[ww][l];
      r[0] += o[0]; r[1] += o[1]; r[2] += o[2]; r[3] += o[3];
    }
    int n = lane16;
    if (n < 10) {
      int sg = sc + s_off;
      float bias = fmaf(__expf(0.5f * blv[n]), bel[sg * 10 + n], blm[n]);
#pragma unroll
      for (int rr = 0; rr < 4; ++rr) {
        int m = m0 + quad * 4 + rr;
        out[((size_t)sg * 1024 + m) * 10 + n] = r[rr] + bias;
      }
    }
  }
}

// ---------- launch ----------
extern "C" void kernel_launch(void* const* d_in, const int* in_sizes, int n_in,
                              void* d_out, int out_size, void* d_ws, size_t ws_size,
                              hipStream_t stream) {
  const float* x   = (const float*)d_in[0];
  const float* wm0 = (const float*)d_in[1];
  const float* wv0 = (const float*)d_in[2];
  const float* bm0 = (const float*)d_in[3];
  const float* bv0 = (const float*)d_in[4];
  const float* wm1 = (const float*)d_in[5];
  const float* wv1 = (const float*)d_in[6];
  const float* bm1 = (const float*)d_in[7];
  const float* bv1 = (const float*)d_in[8];
  const float* wlm = (const float*)d_in[9];
  const float* wlv = (const float*)d_in[10];
  const float* blm = (const float*)d_in[11];
  const float* blv = (const float*)d_in[12];
  const float* we0 = (const float*)d_in[13];
  const float* be0 = (const float*)d_in[14];
  const float* we1 = (const float*)d_in[15];
  const float* be1 = (const float*)d_in[16];
  const float* wel = (const float*)d_in[17];
  const float* bel = (const float*)d_in[18];
  float* out = (float*)d_out;

  // workspace layout
  const size_t sz_x    = (size_t)1024 * 800 * 2;
  const size_t sz_W0t  = (size_t)1024 * 800 * 2;   // per s (25 tiles * 1024 * 32)
  const size_t sz_act  = (size_t)1024 * 1024 * 2;  // per s
  const size_t sz_Wlt  = (size_t)16 * 1024 * 2;    // per s
  const size_t per_s = sz_W0t + 3 * sz_act + sz_Wlt;

  int SC = 32;
  while (SC > 1 && sz_x + (size_t)SC * per_s + 4096 > ws_size) SC >>= 1;

  char* ws = (char*)d_ws;
  size_t off = 0;
  auto take = [&](size_t bsz) {
    char* p = ws + off;
    off = (off + bsz + 255) & ~(size_t)255;
    return p;
  };
  u16* xbf  = (u16*)take(sz_x);
  u16* W0t  = (u16*)take((size_t)SC * sz_W0t);
  u16* act1 = (u16*)take((size_t)SC * sz_act);
  u16* W1t  = (u16*)take((size_t)SC * sz_act);
  u16* act2 = (u16*)take((size_t)SC * sz_act);
  u16* Wlt  = (u16*)take((size_t)SC * sz_Wlt);

  pad_x_k<<<3200, 256, 0, stream>>>(x, xbf);

  const int gs = (SC >= 8) ? 8 : SC;
  const int KB0 = 25;   // 800 / 32
  const int KB1 = 32;   // 1024 / 32

  for (int s0 = 0; s0 < 32; s0 += SC) {
    // layer 0: K=784 (Kp=800), N=1024
    sample_wt_k<<<gs * KB0 * 4, 256, 0, stream>>>(
        we0 + (size_t)s0 * 784 * 1024, wm0, wv0, W0t, 784, KB0, SC);
    gemm_bt_relu<<<64 * SC, 256, 0, stream>>>(
        xbf, (size_t)0, 800, W0t, act1, 800, bm0, bv0, be0, s0, SC);
    // layer 1: K=1024, N=1024
    sample_wt_k<<<gs * KB1 * 4, 256, 0, stream>>>(
        we1 + (size_t)s0 * 1024 * 1024, wm1, wv1, W1t, 1024, KB1, SC);
    gemm_bt_relu<<<64 * SC, 256, 0, stream>>>(
        act1, (size_t)1024 * 1024, 1024, W1t, act2, 1024, bm1, bv1, be1, s0, SC);
    // last layer
    sample_wl_k<<<SC * 64, 256, 0, stream>>>(
        wel + (size_t)s0 * 1024 * 10, wlm, wlv, Wlt);
    gemm_last_k<<<64 * SC, 256, 0, stream>>>(
        act2, Wlt, out, blm, blv, bel, s0);
  }
}

// Round 5
// 572.522 us; speedup vs baseline: 1.6381x; 1.1258x over previous
//
#include <hip/hip_runtime.h>

typedef unsigned short u16;
typedef __bf16 bf16x8 __attribute__((ext_vector_type(8)));
typedef float f32x4 __attribute__((ext_vector_type(4)));
typedef u16 u16x8 __attribute__((ext_vector_type(8)));

// ---------- helpers ----------
__device__ __forceinline__ u16 f2bf(float f) {
  unsigned u = __builtin_bit_cast(unsigned, f);
  return (u16)((u + 0x7fffu + ((u >> 16) & 1u)) >> 16);
}

__device__ __forceinline__ void async_load16(const void* g, void* l) {
  __builtin_amdgcn_global_load_lds((const __attribute__((address_space(1))) void*)g,
                                   (__attribute__((address_space(3))) void*)l,
                                   16, 0, 0);
}

// ---------- pad + cast x: (1024,784) f32 -> (1024,800) bf16 ----------
__global__ void pad_x_k(const float* __restrict__ x, u16* __restrict__ xbf) {
  int idx = blockIdx.x * 256 + threadIdx.x;          // 1024*800
  int m = idx / 800, k = idx - m * 800;
  float v = (k < 784) ? x[m * 784 + k] : 0.f;
  xbf[idx] = f2bf(v);
}

// ---------- fused sample + transpose into GEMM-tiled layout ----------
// wt per sample: [KB][1024 n][32 k] bf16, wt[s][kb][n][j] = sample(W[kb*32+j][n]).
// One block = one (sample, kb, 256-n strip): full grid (SC*KB*4 blocks, 16/CU),
// no register amortization (round-2/3 lesson: spg-merging kills parallelism).
// Lane owns row n: 32 coalesced 4B reads along n, 64B contiguous write.
// Block->XCD lane: b&7 == s%8, matching the GEMM reader's XCD L2.
__global__ __launch_bounds__(256) void sample_wt_k(
    const float* __restrict__ we,   // chunk base: (SC,K,N)
    const float* __restrict__ wm,   // (K,N)
    const float* __restrict__ wv,   // (K,N)
    u16* __restrict__ wt,           // (SC,KB,1024,32)
    int K, int KB, int SC) {
  const int N = 1024;
  const int b = blockIdx.x;
  int s, kb, nb;
  if (SC >= 8) {
    int g = b & 7, r = b >> 3, spq = SC >> 3;
    int sq = r % spq, r2 = r / spq;
    nb = r2 & 3; kb = r2 >> 2;
    s = g + sq * 8;
  } else {
    s = b % SC; int r = b / SC; nb = r & 3; kb = r >> 2;
  }
  const int t = threadIdx.x;
  const int n = nb * 256 + t;
  const int kbase = kb * 32;
  const float* we_s = we + (size_t)s * K * N;

  u16 pk[32];
#pragma unroll
  for (int jo = 0; jo < 4; ++jo) {
    float v[8];
#pragma unroll
    for (int j = 0; j < 8; ++j) {
      int k = kbase + jo * 8 + j;
      v[j] = 0.f;
      if (k < K) {
        size_t idx = (size_t)k * N + n;
        v[j] = fmaf(__expf(0.5f * wv[idx]), we_s[idx], wm[idx]);
      }
    }
#pragma unroll
    for (int j = 0; j < 8; ++j) pk[jo * 8 + j] = f2bf(v[j]);
  }
  u16* dst = wt + ((size_t)s * KB + kb) * ((size_t)N * 32) + (size_t)n * 32;
#pragma unroll
  for (int q = 0; q < 4; ++q)
    *(u16x8*)(dst + q * 8) = *(const u16x8*)(pk + q * 8);
}

// ---------- sample last-layer W -> Wlt[s][16][1024] bf16 (n>=10 zero) ----------
__global__ void sample_wl_k(const float* __restrict__ wel,  // chunk base (SC,1024,10)
                            const float* __restrict__ wlm,  // (1024,10)
                            const float* __restrict__ wlv,  // (1024,10)
                            u16* __restrict__ wlt) {        // (SC,16,1024)
  int idx = blockIdx.x * 256 + threadIdx.x;   // SC*16*1024
  int k = idx & 1023;
  int n = (idx >> 10) & 15;
  int s = idx >> 14;
  float v = 0.f;
  if (n < 10) {
    size_t i2 = ((size_t)s * 1024 + k) * 10 + n;
    size_t iw = (size_t)k * 10 + n;
    v = fmaf(__expf(0.5f * wlv[iw]), wel[i2], wlm[iw]);
  }
  wlt[idx] = f2bf(v);
}

// ---------- batched GEMM: C[s] = relu(A[s] @ W[s] + bias[s]) ----------
// A: (1024, Kp) bf16 row-major (strideAs==0 -> shared A).
// Bt: tiled (Kp/32, 1024, 32) bf16 per sample. C: (1024,1024) bf16.
// 1D grid, XCD swizzle: sample s -> XCD s%8 (one sample's 4MB WS in one L2).
__global__ __launch_bounds__(256) void gemm_bt_relu(
    const u16* __restrict__ A, size_t strideAs, int ldA,
    const u16* __restrict__ Bt,
    u16* __restrict__ C,
    int Kp,
    const float* __restrict__ bm, const float* __restrict__ bv,
    const float* __restrict__ be, int s_off, int SC) {
  __shared__ __align__(16) u16 As[128 * 32];
  __shared__ __align__(16) u16 Bs[128 * 32];

  const int b = blockIdx.x;
  int sc, tile;
  if (SC >= 8) { sc = (b & 7) + ((b >> 9) << 3); tile = (b >> 3) & 63; }
  else         { sc = b >> 6; tile = b & 63; }
  const int sg = sc + s_off;
  const u16* A_s = A + (size_t)sc * strideAs;
  const u16* B_s = Bt + (size_t)sc * (size_t)1024 * Kp;  // per-sample tiled block
  u16* C_s = C + (size_t)sc * (size_t)1024 * 1024;

  const int m0 = (tile >> 3) * 128;
  const int n0 = (tile & 7) * 128;
  const int t = threadIdx.x;
  const int w = t >> 6, l = t & 63;
  const int quad = l >> 4, lane16 = l & 15;
  const int wm_ = (w >> 1) * 64, wn_ = (w & 1) * 64;

  f32x4 acc[4][4];
#pragma unroll
  for (int i = 0; i < 4; ++i)
#pragma unroll
    for (int j = 0; j < 4; ++j) acc[i][j] = (f32x4){0.f, 0.f, 0.f, 0.f};

  for (int k0 = 0; k0 < Kp; k0 += 32) {
    const u16* Bk = B_s + (size_t)(k0 >> 5) * (1024 * 32);
    __syncthreads();  // previous tile's readers done
#pragma unroll
    for (int i = 0; i < 2; ++i) {
      int p = w * 128 + i * 64 + l;                 // 16B chunk id
      const u16* srcA = A_s + (size_t)(m0 + (p >> 2)) * ldA + k0 + (p & 3) * 8;
      async_load16(srcA, &As[(size_t)(w * 128 + i * 64) * 8]);
      const u16* srcB = Bk + (size_t)(n0 + (p >> 2)) * 32 + (p & 3) * 8;
      async_load16(srcB, &Bs[(size_t)(w * 128 + i * 64) * 8]);
    }
    __syncthreads();  // staging complete

    bf16x8 af[4], bfr[4];
#pragma unroll
    for (int mi = 0; mi < 4; ++mi)
      af[mi] = *(const bf16x8*)&As[(wm_ + mi * 16 + lane16) * 32 + quad * 8];
#pragma unroll
    for (int ni = 0; ni < 4; ++ni)
      bfr[ni] = *(const bf16x8*)&Bs[(wn_ + ni * 16 + lane16) * 32 + quad * 8];
#pragma unroll
    for (int mi = 0; mi < 4; ++mi)
#pragma unroll
      for (int ni = 0; ni < 4; ++ni)
        acc[mi][ni] =
            __builtin_amdgcn_mfma_f32_16x16x32_bf16(af[mi], bfr[ni], acc[mi][ni], 0, 0, 0);
  }

  // epilogue: bias (sampled on the fly) + relu + bf16 store
#pragma unroll
  for (int ni = 0; ni < 4; ++ni) {
    int n = n0 + wn_ + ni * 16 + lane16;
    float bias = fmaf(__expf(0.5f * bv[n]), be[(size_t)sg * 1024 + n], bm[n]);
#pragma unroll
    for (int mi = 0; mi < 4; ++mi) {
#pragma unroll
      for (int r = 0; r < 4; ++r) {
        int m = m0 + wm_ + mi * 16 + quad * 4 + r;
        float v = acc[mi][ni][r] + bias;
        v = fmaxf(v, 0.f);
        C_s[(size_t)m * 1024 + n] = f2bf(v);
      }
    }
  }
}

// ---------- final layer: logits[s] = act2[s] @ Wl[s] + bl[s], N=10 ----------
// One 16-row m-tile per block; 4 waves split K=1024; LDS reduce.
__global__ __launch_bounds__(256) void gemm_last_k(
    const u16* __restrict__ act2, const u16* __restrict__ Wlt,
    float* __restrict__ out,
    const float* __restrict__ blm, const float* __restrict__ blv,
    const float* __restrict__ bel, int s_off) {
  __shared__ f32x4 red[4][64];
  const int b = blockIdx.x;
  const int sc = b >> 6, tile = b & 63;
  const int t = threadIdx.x;
  const int w = t >> 6, l = t & 63;
  const int quad = l >> 4, lane16 = l & 15;
  const int m0 = tile * 16;

  const u16* A_s = act2 + (size_t)sc * 1024 * 1024;
  const u16* B_s = Wlt + (size_t)sc * 16 * 1024;

  f32x4 acc = (f32x4){0.f, 0.f, 0.f, 0.f};
  const int kbase = w * 256;
#pragma unroll
  for (int k0 = 0; k0 < 256; k0 += 32) {
    int k = kbase + k0;
    bf16x8 a = *(const bf16x8*)&A_s[(size_t)(m0 + lane16) * 1024 + k + quad * 8];
    bf16x8 bb = *(const bf16x8*)&B_s[(size_t)lane16 * 1024 + k + quad * 8];
    acc = __builtin_amdgcn_mfma_f32_16x16x32_bf16(a, bb, acc, 0, 0, 0);
  }
  red[w][l] = acc;
  __syncthreads();
  if (w == 0) {
    f32x4 r = red[0][l];
#pragma unroll
    for (int ww = 1; ww < 4; ++ww) {
      f32x4 o = red[ww][l];
      r[0] += o[0]; r[1] += o[1]; r[2] += o[2]; r[3] += o[3];
    }
    int n = lane16;
    if (n < 10) {
      int sg = sc + s_off;
      float bias = fmaf(__expf(0.5f * blv[n]), bel[sg * 10 + n], blm[n]);
#pragma unroll
      for (int rr = 0; rr < 4; ++rr) {
        int m = m0 + quad * 4 + rr;
        out[((size_t)sg * 1024 + m) * 10 + n] = r[rr] + bias;
      }
    }
  }
}

// ---------- launch ----------
extern "C" void kernel_launch(void* const* d_in, const int* in_sizes, int n_in,
                              void* d_out, int out_size, void* d_ws, size_t ws_size,
                              hipStream_t stream) {
  const float* x   = (const float*)d_in[0];
  const float* wm0 = (const float*)d_in[1];
  const float* wv0 = (const float*)d_in[2];
  const float* bm0 = (const float*)d_in[3];
  const float* bv0 = (const float*)d_in[4];
  const float* wm1 = (const float*)d_in[5];
  const float* wv1 = (const float*)d_in[6];
  const float* bm1 = (const float*)d_in[7];
  const float* bv1 = (const float*)d_in[8];
  const float* wlm = (const float*)d_in[9];
  const float* wlv = (const float*)d_in[10];
  const float* blm = (const float*)d_in[11];
  const float* blv = (const float*)d_in[12];
  const float* we0 = (const float*)d_in[13];
  const float* be0 = (const float*)d_in[14];
  const float* we1 = (const float*)d_in[15];
  const float* be1 = (const float*)d_in[16];
  const float* wel = (const float*)d_in[17];
  const float* bel = (const float*)d_in[18];
  float* out = (float*)d_out;

  // workspace layout
  const size_t sz_x    = (size_t)1024 * 800 * 2;
  const size_t sz_W0t  = (size_t)1024 * 800 * 2;   // per s (25 tiles * 1024 * 32)
  const size_t sz_act  = (size_t)1024 * 1024 * 2;  // per s
  const size_t sz_Wlt  = (size_t)16 * 1024 * 2;    // per s
  const size_t per_s = sz_W0t + 3 * sz_act + sz_Wlt;

  int SC = 32;
  while (SC > 1 && sz_x + (size_t)SC * per_s + 4096 > ws_size) SC >>= 1;

  char* ws = (char*)d_ws;
  size_t off = 0;
  auto take = [&](size_t bsz) {
    char* p = ws + off;
    off = (off + bsz + 255) & ~(size_t)255;
    return p;
  };
  u16* xbf  = (u16*)take(sz_x);
  u16* W0t  = (u16*)take((size_t)SC * sz_W0t);
  u16* act1 = (u16*)take((size_t)SC * sz_act);
  u16* W1t  = (u16*)take((size_t)SC * sz_act);
  u16* act2 = (u16*)take((size_t)SC * sz_act);
  u16* Wlt  = (u16*)take((size_t)SC * sz_Wlt);

  pad_x_k<<<3200, 256, 0, stream>>>(x, xbf);

  const int KB0 = 25;   // 800 / 32
  const int KB1 = 32;   // 1024 / 32

  for (int s0 = 0; s0 < 32; s0 += SC) {
    // layer 0: K=784 (Kp=800), N=1024
    sample_wt_k<<<SC * KB0 * 4, 256, 0, stream>>>(
        we0 + (size_t)s0 * 784 * 1024, wm0, wv0, W0t, 784, KB0, SC);
    gemm_bt_relu<<<64 * SC, 256, 0, stream>>>(
        xbf, (size_t)0, 800, W0t, act1, 800, bm0, bv0, be0, s0, SC);
    // layer 1: K=1024, N=1024
    sample_wt_k<<<SC * KB1 * 4, 256, 0, stream>>>(
        we1 + (size_t)s0 * 1024 * 1024, wm1, wv1, W1t, 1024, KB1, SC);
    gemm_bt_relu<<<64 * SC, 256, 0, stream>>>(
        act1, (size_t)1024 * 1024, 1024, W1t, act2, 1024, bm1, bv1, be1, s0, SC);
    // last layer
    sample_wl_k<<<SC * 64, 256, 0, stream>>>(
        wel + (size_t)s0 * 1024 * 10, wlm, wlv, Wlt);
    gemm_last_k<<<64 * SC, 256, 0, stream>>>(
        act2, Wlt, out, blm, blv, bel, s0);
  }
}